// Round 3
// baseline (502.094 us; speedup 1.0000x reference)
//
#include <hip/hip_runtime.h>
#include <math.h>

#define B 32
#define H 8
#define N 512
#define TPB 512
#define RPB 64
#define NBLK (B * H)  // 256 blocks, 1 per CU

// 8-block (one b-group) barrier: device-scope release/acquire via global counter.
__device__ __forceinline__ void group_barrier(int* cnt, int target) {
    __syncthreads();
    if (threadIdx.x == 0) {
        __threadfence();                       // release: partials visible device-wide
        atomicAdd(cnt, 1);                     // device scope by default
        while (__hip_atomic_load(cnt, __ATOMIC_ACQUIRE, __HIP_MEMORY_SCOPE_AGENT) < target)
            __builtin_amdgcn_s_sleep(1);
    }
    __syncthreads();
    __threadfence();                           // acquire side for all lanes
}

__global__ __launch_bounds__(TPB) void k_all(const float* __restrict__ in,
                                             float* __restrict__ out,
                                             int* __restrict__ counters) {
    __shared__ float Gs[RPB][N];   // 128 KB: this block's 64 rows of G[b] = sum_h exp(x)
    __shared__ float E0g[N];       // exp(x[b, g, 0, :])  (head h=g row-0 slice)
    __shared__ float vec[N];       // current c factors
    __shared__ float EcS[H][RPB];  // exp(x[b, h, rbase+il, 0])
    __shared__ float rloc[RPB];
    __shared__ float c0rec[H];
    __shared__ float r0s[H];
    __shared__ float r0loc_s;

    const int blk = blockIdx.x;
    const int b = blk >> 3;
    const int g = blk & 7;
    const int rbase = g * RPB;
    const bool owner = (g == 0);
    const int tid = threadIdx.x;
    const int w = tid >> 6, lane = tid & 63;

    // group-local scratch inside this group's OWN slice of d_out (overwritten only
    // by this group's blocks, after the final group barrier)
    float* gbase = out + (size_t)b * (H * N * N);
    float* pA  = gbase;             // 8*N partial col sums
    float* pB  = gbase + 8 * N;
    float* c0A = gbase + 16 * N;    // 8*8 partial c0 sums
    float* c0B = c0A + 64;
    float* r0g = c0B + 64;          // 8 final r0 values
    int* cnt = counters + b * 16;   // 64B-padded counter per group

    // ---- build phase: G rows + E slices straight from input into LDS ----
    const int il4 = tid >> 7;      // 0..3
    const int j4 = tid & 127;      // float4 column index
    const size_t inb = (size_t)b * H * N * N;
    for (int ilb = 0; ilb < RPB; ilb += 4) {
        const int il = ilb + il4;
        const int i = rbase + il;
        float4 acc = make_float4(0.f, 0.f, 0.f, 0.f);
#pragma unroll
        for (int h = 0; h < H; ++h) {
            const float4 x = *reinterpret_cast<const float4*>(
                in + inb + ((size_t)h * N + i) * N + j4 * 4);
            float ex = __expf(x.x), ey = __expf(x.y), ez = __expf(x.z), ew = __expf(x.w);
            acc.x += ex; acc.y += ey; acc.z += ez; acc.w += ew;
            if (j4 == 0) EcS[h][il] = ex;
        }
        *reinterpret_cast<float4*>(&Gs[il][j4 * 4]) = acc;
    }
    E0g[tid] = __expf(in[inb + (size_t)g * N * N + tid]);  // head g, row 0
    __syncthreads();
    const float E00g = E0g[0];     // exp(x[b, g, 0, 0])

    float* parts[2] = {pA, pB};
    float* c0ps[2] = {c0A, c0B};

    for (int it = 0; it < 5; ++it) {
        // ---------- row phase: r[b,i] (local rows) and r0[b,g] ----------
        if (it == 0) {
            vec[tid] = (tid == 0) ? 0.0f : 1.0f;   // c = 1; j=0 handled via c0 term
            if (tid < H) c0rec[tid] = 1.0f;
        } else {
            const float* p = parts[it & 1];
            float cs = 0.0f;
#pragma unroll
            for (int gg = 0; gg < 8; ++gg) cs += p[gg * N + tid];
            vec[tid] = (tid == 0) ? 0.0f : 1.0f / cs;
            if (tid < H) {
                const float* q = c0ps[it & 1];
                float s = 0.0f;
#pragma unroll
                for (int gg = 0; gg < 8; ++gg) s += q[gg * H + tid];
                c0rec[tid] = 1.0f / s;
            }
        }
        __syncthreads();
        float cj[8];
#pragma unroll
        for (int k = 0; k < 8; ++k) cj[k] = vec[lane + 64 * k];
#pragma unroll
        for (int r8 = 0; r8 < 8; ++r8) {
            const int il = w * 8 + r8;
            float pacc = 0.0f;
#pragma unroll
            for (int k = 0; k < 8; ++k) pacc += Gs[il][lane + 64 * k] * cj[k];
#pragma unroll
            for (int s = 32; s > 0; s >>= 1) pacc += __shfl_down(pacc, s, 64);
            if (lane == 0) {
                float s2 = pacc;
#pragma unroll
                for (int h = 0; h < H; ++h) s2 += EcS[h][il] * c0rec[h];
                rloc[il] = 1.0f / s2;   // garbage for owner il=0 (i=0), masked below
            }
        }
        if (w == g) {   // r0 for head h=g
            float pacc = 0.0f;
#pragma unroll
            for (int k = 0; k < 8; ++k) pacc += E0g[lane + 64 * k] * cj[k];
#pragma unroll
            for (int s = 32; s > 0; s >>= 1) pacc += __shfl_down(pacc, s, 64);
            if (lane == 0) {
                float v = 1.0f / (pacc + E00g * c0rec[g]);
                r0loc_s = v;
                if (it == 4) r0g[g] = v;   // publish final r0 for the group
            }
        }
        __syncthreads();
        // ---------- col phase: partial column sums ----------
        {
            const float r0l = r0loc_s;
            float acc = 0.0f;
            const int il0 = owner ? 1 : 0;   // global row 0 handled via E0 terms
#pragma unroll 8
            for (int il = il0; il < RPB; ++il) acc += Gs[il][tid] * rloc[il];
            acc += E0g[tid] * r0l;           // head g's i=0 contribution
            parts[(it + 1) & 1][g * N + tid] = acc;
            float q = EcS[w][lane] * ((owner && lane == 0) ? 0.0f : rloc[lane]);
            if (w == g && lane == 0) q += E00g * r0l;
#pragma unroll
            for (int s = 32; s > 0; s >>= 1) q += __shfl_down(q, s, 64);
            if (lane == 0) c0ps[(it + 1) & 1][g * H + w] = q;
        }
        group_barrier(cnt, (it + 1) * 8);
    }

    // ---- finalize c factors (every block computes its own copy) ----
    {
        const float* p = parts[1];           // (4+1)&1 == 1
        float cs = 0.0f;
#pragma unroll
        for (int gg = 0; gg < 8; ++gg) cs += p[gg * N + tid];
        vec[tid] = (tid == 0) ? 1.0f : 1.0f / cs;   // vec[0] replaced per-head below
        if (tid < H) {
            const float* q = c0ps[1];
            float s = 0.0f;
#pragma unroll
            for (int gg = 0; gg < 8; ++gg) s += q[gg * H + tid];
            c0rec[tid] = 1.0f / s;
            r0s[tid] = r0g[tid];
        }
    }
    // all reads of group scratch done before block (b,0) overwrites it
    group_barrier(cnt, 48);

    // ---- final streaming: out = exp(x) * R_i * C_j over owned rows, all heads ----
    for (int h = 0; h < H; ++h) {
        const float r0h = r0s[h];
        const float c0h = c0rec[h];
#pragma unroll 4
        for (int ilb = 0; ilb < RPB; ilb += 4) {
            const int il = ilb + il4;
            const int i = rbase + il;
            const float R = (i == 0) ? r0h : rloc[il];
            const size_t off = inb + ((size_t)h * N + i) * N + j4 * 4;
            const float4 x = *reinterpret_cast<const float4*>(in + off);
            float4 c4 = *reinterpret_cast<const float4*>(&vec[j4 * 4]);
            if (j4 == 0) c4.x = c0h;
            float4 o;
            o.x = __expf(x.x) * R * c4.x;
            o.y = __expf(x.y) * R * c4.y;
            o.z = __expf(x.z) * R * c4.z;
            o.w = __expf(x.w) * R * c4.w;
            *reinterpret_cast<float4*>(out + off) = o;
        }
    }
}

extern "C" void kernel_launch(void* const* d_in, const int* in_sizes, int n_in,
                              void* d_out, int out_size, void* d_ws, size_t ws_size,
                              hipStream_t stream) {
    (void)in_sizes; (void)n_in; (void)out_size; (void)ws_size;
    const float* in = (const float*)d_in[0];
    float* out = (float*)d_out;
    int* counters = (int*)d_ws;   // 32 groups x 16 ints (64B padding)

    hipMemsetAsync(counters, 0, B * 16 * sizeof(int), stream);

    void* args[] = {(void*)&in, (void*)&out, (void*)&counters};
    hipLaunchCooperativeKernel(reinterpret_cast<void*>(k_all), dim3(NBLK), dim3(TPB),
                               args, 0, stream);
}

// Round 4
// 407.017 us; speedup vs baseline: 1.2336x; 1.2336x over previous
//
#include <hip/hip_runtime.h>
#include <hip/hip_cooperative_groups.h>
#include <math.h>

#define B 32
#define H 8
#define N 512
#define NBLK 256   // cooperative blocks (1 per CU)
#define TPB 512
#define RPB 64     // G rows per cooperative block
// d_out tail scratch layout (floats):
#define OFF_E0   8388608           // B*N*N
#define OFF_EC   (OFF_E0 + 131072)
#define OFF_PA   (OFF_EC + 131072)
#define OFF_PB   (OFF_PA + 131072)
#define OFF_C0A  (OFF_PB + 131072)
#define OFF_C0B  (OFF_C0A + 2048)

// 8-block (one b-group) barrier: device-scope release/acquire via global counter.
__device__ __forceinline__ void group_barrier(int* cnt, int target) {
    __syncthreads();
    if (threadIdx.x == 0) {
        __threadfence();                       // release: partials visible device-wide
        atomicAdd(cnt, 1);                     // device scope by default
        while (__hip_atomic_load(cnt, __ATOMIC_ACQUIRE, __HIP_MEMORY_SCOPE_AGENT) < target)
            __builtin_amdgcn_s_sleep(1);
    }
    __syncthreads();
    __threadfence();                           // acquire side for all lanes
}

// Build G[b,i,j] = sum_h exp(x); E0[b,h,j] = exp(x[b,h,0,j]); Ec[b,h,i] = exp(x[b,h,i,0]).
// float4 everywhere; 128-thread blocks, one (b,i) row per block -> full occupancy.
__global__ __launch_bounds__(128) void k_build(const float* __restrict__ in,
                                               float* __restrict__ G,
                                               float* __restrict__ E0,
                                               float* __restrict__ Ec) {
    const int i = blockIdx.x;
    const int b = blockIdx.y;
    const int t = threadIdx.x;          // float4 column index, 0..127
    const size_t inb = (size_t)b * H * N * N;
    float4 acc = make_float4(0.f, 0.f, 0.f, 0.f);
#pragma unroll
    for (int h = 0; h < H; ++h) {
        const float4 x = *reinterpret_cast<const float4*>(
            in + inb + ((size_t)h * N + i) * N + t * 4);
        float4 e;
        e.x = __expf(x.x); e.y = __expf(x.y); e.z = __expf(x.z); e.w = __expf(x.w);
        acc.x += e.x; acc.y += e.y; acc.z += e.z; acc.w += e.w;
        if (t == 0) Ec[(b * H + h) * N + i] = e.x;
        if (i == 0) *reinterpret_cast<float4*>(E0 + (b * H + h) * N + t * 4) = e;
    }
    *reinterpret_cast<float4*>(G + ((size_t)b * N + i) * N + t * 4) = acc;
}

// 5 x (row-normalize, col-normalize) with G LDS-resident; 8-block group barriers.
__global__ __launch_bounds__(TPB) void k_coop(const float* __restrict__ G,
                                              const float* __restrict__ E0,
                                              const float* __restrict__ Ec,
                                              float* __restrict__ partA,
                                              float* __restrict__ partB,
                                              float* __restrict__ c0pA,
                                              float* __restrict__ c0pB,
                                              float* __restrict__ rv,
                                              float* __restrict__ r0v,
                                              float* __restrict__ cv,
                                              float* __restrict__ c0v,
                                              int* __restrict__ counters) {
    __shared__ float Gs[RPB][N];   // 128 KB
    __shared__ float E0g[N];       // this block's head (h=g) row-0 slice
    __shared__ float vec[N];       // c values (row phase)
    __shared__ float EcS[H][RPB];  // Ec for owned rows
    __shared__ float rloc[RPB];
    __shared__ float c0rec[H];
    __shared__ float r0loc_s;

    const int blk = blockIdx.x;
    const int b = blk >> 3;
    const int g = blk & 7;
    const int rbase = g * RPB;
    const bool owner = (g == 0);
    const int tid = threadIdx.x;
    const int w = tid >> 6, lane = tid & 63;
    int* cnt = counters + b * 16;

    // ---- load LDS-resident state ----
    {
        const float4* Gg = reinterpret_cast<const float4*>(G + ((size_t)(b * N) + rbase) * N);
        float4* Gl = reinterpret_cast<float4*>(&Gs[0][0]);
        for (int t = tid; t < RPB * N / 4; t += TPB) Gl[t] = Gg[t];
    }
    for (int t = tid; t < H * RPB; t += TPB)
        EcS[t / RPB][t % RPB] = Ec[(b * H + (t / RPB)) * N + rbase + (t % RPB)];
    E0g[tid] = E0[(b * H + g) * N + tid];
    const float E00g = Ec[(b * H + g) * N];  // E[b,g,0,0]
    __syncthreads();

    float* parts[2] = {partA, partB};
    float* c0ps[2] = {c0pA, c0pB};

    for (int it = 0; it < 5; ++it) {
        // ---------- row phase: r[b,i] and r0[b,h] ----------
        if (it == 0) {
            vec[tid] = (tid == 0) ? 0.0f : 1.0f;  // c = 1; j=0 masked (handled via c0 term)
            if (tid < H) c0rec[tid] = 1.0f;
        } else {
            const float* p = parts[it & 1] + (size_t)b * 8 * N;
            float cs = 0.0f;
#pragma unroll
            for (int gg = 0; gg < 8; ++gg) cs += p[gg * N + tid];
            vec[tid] = (tid == 0) ? 0.0f : 1.0f / cs;
            if (tid < H) {
                const float* q = c0ps[it & 1] + b * 8 * H;
                float s = 0.0f;
#pragma unroll
                for (int gg = 0; gg < 8; ++gg) s += q[gg * H + tid];
                c0rec[tid] = 1.0f / s;
            }
        }
        __syncthreads();
        float cj[8];
#pragma unroll
        for (int k = 0; k < 8; ++k) cj[k] = vec[lane + 64 * k];
#pragma unroll
        for (int r8 = 0; r8 < 8; ++r8) {
            const int il = w * 8 + r8;
            float pacc = 0.0f;
#pragma unroll
            for (int k = 0; k < 8; ++k) pacc += Gs[il][lane + 64 * k] * cj[k];
#pragma unroll
            for (int s = 32; s > 0; s >>= 1) pacc += __shfl_down(pacc, s, 64);
            if (lane == 0) {
                float s2 = pacc;
#pragma unroll
                for (int h = 0; h < H; ++h) s2 += EcS[h][il] * c0rec[h];
                float rva = 1.0f / s2;
                rloc[il] = rva;                 // garbage for owner il=0, masked below
                if (it == 4) rv[b * N + rbase + il] = rva;
            }
        }
        if (w == g) {   // r0 for head h=g
            float pacc = 0.0f;
#pragma unroll
            for (int k = 0; k < 8; ++k) pacc += E0g[lane + 64 * k] * cj[k];
#pragma unroll
            for (int s = 32; s > 0; s >>= 1) pacc += __shfl_down(pacc, s, 64);
            if (lane == 0) {
                float v = 1.0f / (pacc + E00g * c0rec[g]);
                r0loc_s = v;
                if (it == 4) r0v[b * H + g] = v;
            }
        }
        __syncthreads();
        // ---------- col phase: partial column sums ----------
        {
            const float r0l = r0loc_s;
            float acc = 0.0f;
            const int il0 = owner ? 1 : 0;  // global row 0 handled via E0 terms
#pragma unroll 8
            for (int il = il0; il < RPB; ++il) acc += Gs[il][tid] * rloc[il];
            acc += E0g[tid] * r0l;          // head g's i=0 contribution
            parts[(it + 1) & 1][((size_t)(b * 8) + g) * N + tid] = acc;
            float q = EcS[w][lane] * ((owner && lane == 0) ? 0.0f : rloc[lane]);
            if (w == g && lane == 0) q += E00g * r0l;
#pragma unroll
            for (int s = 32; s > 0; s >>= 1) q += __shfl_down(q, s, 64);
            if (lane == 0) c0ps[(it + 1) & 1][(b * 8 + g) * H + w] = q;
        }
        group_barrier(cnt, (it + 1) * 8);
    }
    // ---- finalize c factors (block g==0 of each b) ----
    if (owner) {
        const float* p = parts[1] + (size_t)b * 8 * N;  // (4+1)&1 == 1
        float cs = 0.0f;
#pragma unroll
        for (int gg = 0; gg < 8; ++gg) cs += p[gg * N + tid];
        cv[b * N + tid] = (tid == 0) ? 1.0f : 1.0f / cs;
        if (tid < H) {
            const float* q = c0ps[1] + b * 8 * H;
            float s = 0.0f;
#pragma unroll
            for (int gg = 0; gg < 8; ++gg) s += q[gg * H + tid];
            c0v[b * H + tid] = 1.0f / s;
        }
    }
}

__global__ __launch_bounds__(256) void k_final(const float* __restrict__ in,
                                               const float* __restrict__ rv,
                                               const float* __restrict__ r0v,
                                               const float* __restrict__ cv,
                                               const float* __restrict__ c0v,
                                               float* __restrict__ out) {
    const size_t v = (size_t)blockIdx.x * 256 + threadIdx.x;  // float4 index
    const int j4 = (int)(v & 127);
    size_t rest = v >> 7;
    const int i = (int)(rest & 511); rest >>= 9;
    const int h = (int)(rest & 7);
    const int b = (int)(rest >> 3);
    const float R = (i == 0) ? r0v[b * H + h] : rv[b * N + i];
    const float4 x = reinterpret_cast<const float4*>(in)[v];
    float4 cl = reinterpret_cast<const float4*>(cv + b * N)[j4];
    if (j4 == 0) cl.x = c0v[b * H + h];
    float4 o;
    o.x = __expf(x.x) * R * cl.x;
    o.y = __expf(x.y) * R * cl.y;
    o.z = __expf(x.z) * R * cl.z;
    o.w = __expf(x.w) * R * cl.w;
    reinterpret_cast<float4*>(out)[v] = o;
}

extern "C" void kernel_launch(void* const* d_in, const int* in_sizes, int n_in,
                              void* d_out, int out_size, void* d_ws, size_t ws_size,
                              hipStream_t stream) {
    (void)in_sizes; (void)n_in; (void)out_size; (void)ws_size;
    const float* in = (const float*)d_in[0];
    float* out = (float*)d_out;
    float* ws = (float*)d_ws;

    // persistent factor vectors (must survive into k_final) live in ws
    float* rv  = ws;           // B*N
    float* cv  = ws + 16384;   // B*N
    float* r0v = ws + 32768;   // B*H
    float* c0v = ws + 33024;   // B*H
    int* counters = (int*)(ws + 33280);  // 32 groups x 16 ints

    // pre-final scratch lives in the tail of d_out (fully consumed before k_final writes)
    float* G   = out;             // B*N*N
    float* E0  = out + OFF_E0;    // B*H*N
    float* Ec  = out + OFF_EC;    // B*H*N
    float* pA  = out + OFF_PA;    // B*8*N
    float* pB  = out + OFF_PB;    // B*8*N
    float* c0A = out + OFF_C0A;   // B*8*H
    float* c0B = out + OFF_C0B;   // B*8*H

    hipMemsetAsync(counters, 0, B * 16 * sizeof(int), stream);

    k_build<<<dim3(N, B), 128, 0, stream>>>(in, G, E0, Ec);

    void* args[] = {(void*)&G, (void*)&E0, (void*)&Ec, (void*)&pA, (void*)&pB,
                    (void*)&c0A, (void*)&c0B, (void*)&rv, (void*)&r0v,
                    (void*)&cv, (void*)&c0v, (void*)&counters};
    hipLaunchCooperativeKernel(reinterpret_cast<void*>(k_coop), dim3(NBLK), dim3(TPB),
                               args, 0, stream);

    k_final<<<65536, 256, 0, stream>>>(in, rv, r0v, cv, c0v, out);
}

// Round 5
// 223.071 us; speedup vs baseline: 2.2508x; 1.8246x over previous
//
#include <hip/hip_runtime.h>
#include <hip/hip_cooperative_groups.h>
#include <math.h>

#define B 32
#define H 8
#define N 512
#define NBLK 256   // cooperative blocks (1 per CU)
#define TPB 512
#define RPB 64     // G rows per cooperative block
// d_out tail scratch layout (floats):
#define OFF_E0   8388608           // B*N*N
#define OFF_EC   (OFF_E0 + 131072)
#define OFF_PA   (OFF_EC + 131072)
#define OFF_PB   (OFF_PA + 131072)
#define OFF_C0A  (OFF_PB + 131072)
#define OFF_C0B  (OFF_C0A + 2048)

// All cross-block data moves through relaxed agent-scope atomics (sc-bit,
// coherence-point accesses). No fences anywhere -> no L2 writeback/invalidate.
__device__ __forceinline__ float atomLoad(const float* p) {
    return __hip_atomic_load(p, __ATOMIC_RELAXED, __HIP_MEMORY_SCOPE_AGENT);
}
__device__ __forceinline__ void atomStore(float* p, float v) {
    __hip_atomic_store(p, v, __ATOMIC_RELAXED, __HIP_MEMORY_SCOPE_AGENT);
}

// 8-block (one b-group) barrier. __syncthreads() drains vmcnt for every wave,
// so all sc-bit data stores are globally visible before the signal.
__device__ __forceinline__ void group_barrier(int* cnt, int target) {
    __syncthreads();
    if (threadIdx.x == 0) {
        __hip_atomic_fetch_add(cnt, 1, __ATOMIC_RELAXED, __HIP_MEMORY_SCOPE_AGENT);
        while (__hip_atomic_load(cnt, __ATOMIC_RELAXED, __HIP_MEMORY_SCOPE_AGENT) < target)
            __builtin_amdgcn_s_sleep(2);
    }
    __syncthreads();
}

// Build G[b,i,j] = sum_h exp(x); E0[b,h,j] = exp(x[b,h,0,j]); Ec[b,h,i] = exp(x[b,h,i,0]).
__global__ __launch_bounds__(128) void k_build(const float* __restrict__ in,
                                               float* __restrict__ G,
                                               float* __restrict__ E0,
                                               float* __restrict__ Ec) {
    const int i = blockIdx.x;
    const int b = blockIdx.y;
    const int t = threadIdx.x;          // float4 column index, 0..127
    const size_t inb = (size_t)b * H * N * N;
    float4 acc = make_float4(0.f, 0.f, 0.f, 0.f);
#pragma unroll
    for (int h = 0; h < H; ++h) {
        const float4 x = *reinterpret_cast<const float4*>(
            in + inb + ((size_t)h * N + i) * N + t * 4);
        float4 e;
        e.x = __expf(x.x); e.y = __expf(x.y); e.z = __expf(x.z); e.w = __expf(x.w);
        acc.x += e.x; acc.y += e.y; acc.z += e.z; acc.w += e.w;
        if (t == 0) Ec[(b * H + h) * N + i] = e.x;
        if (i == 0) *reinterpret_cast<float4*>(E0 + (b * H + h) * N + t * 4) = e;
    }
    *reinterpret_cast<float4*>(G + ((size_t)b * N + i) * N + t * 4) = acc;
}

// 5 x (row-normalize, col-normalize) with G LDS-resident; fence-free 8-block barriers.
__global__ __launch_bounds__(TPB) void k_coop(const float* __restrict__ G,
                                              const float* __restrict__ E0,
                                              const float* __restrict__ Ec,
                                              float* __restrict__ partA,
                                              float* __restrict__ partB,
                                              float* __restrict__ c0pA,
                                              float* __restrict__ c0pB,
                                              float* __restrict__ rv,
                                              float* __restrict__ r0v,
                                              float* __restrict__ cv,
                                              float* __restrict__ c0v,
                                              int* __restrict__ counters) {
    __shared__ float Gs[RPB][N];   // 128 KB
    __shared__ float E0g[N];       // this block's head (h=g) row-0 slice
    __shared__ float vec[N];       // c values (row phase)
    __shared__ float EcS[H][RPB];  // Ec for owned rows
    __shared__ float rloc[RPB];
    __shared__ float c0rec[H];
    __shared__ float r0loc_s;

    const int blk = blockIdx.x;
    const int b = blk >> 3;
    const int g = blk & 7;
    const int rbase = g * RPB;
    const bool owner = (g == 0);
    const int tid = threadIdx.x;
    const int w = tid >> 6, lane = tid & 63;
    int* cnt = counters + b * 16;

    // ---- load LDS-resident state ----
    {
        const float4* Gg = reinterpret_cast<const float4*>(G + ((size_t)(b * N) + rbase) * N);
        float4* Gl = reinterpret_cast<float4*>(&Gs[0][0]);
        for (int t = tid; t < RPB * N / 4; t += TPB) Gl[t] = Gg[t];
    }
    for (int t = tid; t < H * RPB; t += TPB)
        EcS[t / RPB][t % RPB] = Ec[(b * H + (t / RPB)) * N + rbase + (t % RPB)];
    E0g[tid] = E0[(b * H + g) * N + tid];
    const float E00g = Ec[(b * H + g) * N];  // E[b,g,0,0]
    __syncthreads();

    for (int it = 0; it < 5; ++it) {
        // ---------- row phase: r[b,i] and r0[b,h] ----------
        if (it == 0) {
            vec[tid] = (tid == 0) ? 0.0f : 1.0f;  // c = 1; j=0 handled via c0 term
            if (tid < H) c0rec[tid] = 1.0f;
        } else {
            const float* pr = (it & 1) ? partB : partA;
            pr += (size_t)b * 8 * N;
            float cs = 0.0f;
#pragma unroll
            for (int gg = 0; gg < 8; ++gg) cs += atomLoad(&pr[gg * N + tid]);
            vec[tid] = (tid == 0) ? 0.0f : 1.0f / cs;
            if (tid < H) {
                const float* qr = (it & 1) ? c0pB : c0pA;
                qr += b * 8 * H;
                float s = 0.0f;
#pragma unroll
                for (int gg = 0; gg < 8; ++gg) s += atomLoad(&qr[gg * H + tid]);
                c0rec[tid] = 1.0f / s;
            }
        }
        __syncthreads();
        float cj[8];
#pragma unroll
        for (int k = 0; k < 8; ++k) cj[k] = vec[lane + 64 * k];
#pragma unroll
        for (int r8 = 0; r8 < 8; ++r8) {
            const int il = w * 8 + r8;
            float pacc = 0.0f;
#pragma unroll
            for (int k = 0; k < 8; ++k) pacc += Gs[il][lane + 64 * k] * cj[k];
#pragma unroll
            for (int s = 32; s > 0; s >>= 1) pacc += __shfl_down(pacc, s, 64);
            if (lane == 0) {
                float s2 = pacc;
#pragma unroll
                for (int h = 0; h < H; ++h) s2 += EcS[h][il] * c0rec[h];
                float rva = 1.0f / s2;
                rloc[il] = rva;                 // garbage for owner il=0, masked below
                if (it == 4) rv[b * N + rbase + il] = rva;
            }
        }
        if (w == g) {   // r0 for head h=g
            float pacc = 0.0f;
#pragma unroll
            for (int k = 0; k < 8; ++k) pacc += E0g[lane + 64 * k] * cj[k];
#pragma unroll
            for (int s = 32; s > 0; s >>= 1) pacc += __shfl_down(pacc, s, 64);
            if (lane == 0) {
                float v = 1.0f / (pacc + E00g * c0rec[g]);
                r0loc_s = v;
                if (it == 4) r0v[b * H + g] = v;
            }
        }
        __syncthreads();
        // ---------- col phase: partial column sums ----------
        {
            float* pw = ((it + 1) & 1) ? partB : partA;
            float* qw = ((it + 1) & 1) ? c0pB : c0pA;
            const float r0l = r0loc_s;
            float acc = 0.0f;
            const int il0 = owner ? 1 : 0;  // global row 0 handled via E0 terms
#pragma unroll 8
            for (int il = il0; il < RPB; ++il) acc += Gs[il][tid] * rloc[il];
            acc += E0g[tid] * r0l;          // head g's i=0 contribution
            atomStore(&pw[((size_t)(b * 8) + g) * N + tid], acc);
            float q = EcS[w][lane] * ((owner && lane == 0) ? 0.0f : rloc[lane]);
            if (w == g && lane == 0) q += E00g * r0l;
#pragma unroll
            for (int s = 32; s > 0; s >>= 1) q += __shfl_down(q, s, 64);
            if (lane == 0) atomStore(&qw[(b * 8 + g) * H + w], q);
        }
        group_barrier(cnt, (it + 1) * 8);
    }
    // ---- finalize c factors (block g==0 of each b) ----
    if (owner) {
        const float* pr = partB + (size_t)b * 8 * N;   // (4+1)&1 == 1
        float cs = 0.0f;
#pragma unroll
        for (int gg = 0; gg < 8; ++gg) cs += atomLoad(&pr[gg * N + tid]);
        cv[b * N + tid] = (tid == 0) ? 1.0f : 1.0f / cs;
        if (tid < H) {
            const float* qr = c0pB + b * 8 * H;
            float s = 0.0f;
#pragma unroll
            for (int gg = 0; gg < 8; ++gg) s += atomLoad(&qr[gg * H + tid]);
            c0v[b * H + tid] = 1.0f / s;
        }
    }
}

__global__ __launch_bounds__(256) void k_final(const float* __restrict__ in,
                                               const float* __restrict__ rv,
                                               const float* __restrict__ r0v,
                                               const float* __restrict__ cv,
                                               const float* __restrict__ c0v,
                                               float* __restrict__ out) {
    const size_t v = (size_t)blockIdx.x * 256 + threadIdx.x;  // float4 index
    const int j4 = (int)(v & 127);
    size_t rest = v >> 7;
    const int i = (int)(rest & 511); rest >>= 9;
    const int h = (int)(rest & 7);
    const int b = (int)(rest >> 3);
    const float R = (i == 0) ? r0v[b * H + h] : rv[b * N + i];
    const float4 x = reinterpret_cast<const float4*>(in)[v];
    float4 cl = reinterpret_cast<const float4*>(cv + b * N)[j4];
    if (j4 == 0) cl.x = c0v[b * H + h];
    float4 o;
    o.x = __expf(x.x) * R * cl.x;
    o.y = __expf(x.y) * R * cl.y;
    o.z = __expf(x.z) * R * cl.z;
    o.w = __expf(x.w) * R * cl.w;
    reinterpret_cast<float4*>(out)[v] = o;
}

extern "C" void kernel_launch(void* const* d_in, const int* in_sizes, int n_in,
                              void* d_out, int out_size, void* d_ws, size_t ws_size,
                              hipStream_t stream) {
    (void)in_sizes; (void)n_in; (void)out_size; (void)ws_size;
    const float* in = (const float*)d_in[0];
    float* out = (float*)d_out;
    float* ws = (float*)d_ws;

    // persistent factor vectors (must survive into k_final) live in ws
    float* rv  = ws;           // B*N
    float* cv  = ws + 16384;   // B*N
    float* r0v = ws + 32768;   // B*H
    float* c0v = ws + 33024;   // B*H
    int* counters = (int*)(ws + 33280);  // 32 groups x 16 ints

    // pre-final scratch lives in the tail of d_out (fully consumed before k_final writes)
    float* G   = out;             // B*N*N
    float* E0  = out + OFF_E0;    // B*H*N
    float* Ec  = out + OFF_EC;    // B*H*N
    float* pA  = out + OFF_PA;    // B*8*N
    float* pB  = out + OFF_PB;    // B*8*N
    float* c0A = out + OFF_C0A;   // B*8*H
    float* c0B = out + OFF_C0B;   // B*8*H

    hipMemsetAsync(counters, 0, B * 16 * sizeof(int), stream);

    k_build<<<dim3(N, B), 128, 0, stream>>>(in, G, E0, Ec);

    void* args[] = {(void*)&G, (void*)&E0, (void*)&Ec, (void*)&pA, (void*)&pB,
                    (void*)&c0A, (void*)&c0B, (void*)&rv, (void*)&r0v,
                    (void*)&cv, (void*)&c0v, (void*)&counters};
    hipLaunchCooperativeKernel(reinterpret_cast<void*>(k_coop), dim3(NBLK), dim3(TPB),
                               args, 0, stream);

    k_final<<<65536, 256, 0, stream>>>(in, rv, r0v, cv, c0v, out);
}

// Round 7
// 211.760 us; speedup vs baseline: 2.3711x; 1.0534x over previous
//
#include <hip/hip_runtime.h>
#include <hip/hip_cooperative_groups.h>
#include <math.h>

#define B 32
#define H 8
#define N 512
#define NBLK 256   // cooperative blocks (1 per CU)
#define TPB 512
#define RPB 64     // G rows per cooperative block
// d_out tail scratch layout (floats):
#define OFF_E0   8388608           // B*N*N
#define OFF_EC   (OFF_E0 + 131072)
#define OFF_PA   (OFF_EC + 131072)
#define OFF_PB   (OFF_PA + 131072)
#define OFF_C0A  (OFF_PB + 131072)
#define OFF_C0B  (OFF_C0A + 2048)

typedef float f32x4 __attribute__((ext_vector_type(4)));  // clang vector: ok for nontemporal builtins

// All cross-block data moves through relaxed agent-scope atomics (sc-bit,
// coherence-point accesses). No fences anywhere -> no L2 writeback/invalidate.
__device__ __forceinline__ float atomLoad(const float* p) {
    return __hip_atomic_load(p, __ATOMIC_RELAXED, __HIP_MEMORY_SCOPE_AGENT);
}
__device__ __forceinline__ void atomStore(float* p, float v) {
    __hip_atomic_store(p, v, __ATOMIC_RELAXED, __HIP_MEMORY_SCOPE_AGENT);
}

// 8-block (one b-group) barrier. __syncthreads() drains vmcnt for every wave,
// so all sc-bit data stores are globally visible before the signal.
__device__ __forceinline__ void group_barrier(int* cnt, int target) {
    __syncthreads();
    if (threadIdx.x == 0) {
        __hip_atomic_fetch_add(cnt, 1, __ATOMIC_RELAXED, __HIP_MEMORY_SCOPE_AGENT);
        while (__hip_atomic_load(cnt, __ATOMIC_RELAXED, __HIP_MEMORY_SCOPE_AGENT) < target)
            __builtin_amdgcn_s_sleep(2);
    }
    __syncthreads();
}

// Build G[b,i,j] = sum_h exp(x); E0[b,h,j] = exp(x[b,h,0,j]); Ec[b,h,i] = exp(x[b,h,i,0]).
__global__ __launch_bounds__(128) void k_build(const float* __restrict__ in,
                                               float* __restrict__ G,
                                               float* __restrict__ E0,
                                               float* __restrict__ Ec) {
    const int i = blockIdx.x;
    const int b = blockIdx.y;
    const int t = threadIdx.x;          // float4 column index, 0..127
    const size_t inb = (size_t)b * H * N * N;
    float4 acc = make_float4(0.f, 0.f, 0.f, 0.f);
#pragma unroll
    for (int h = 0; h < H; ++h) {
        const float4 x = *reinterpret_cast<const float4*>(
            in + inb + ((size_t)h * N + i) * N + t * 4);
        float4 e;
        e.x = __expf(x.x); e.y = __expf(x.y); e.z = __expf(x.z); e.w = __expf(x.w);
        acc.x += e.x; acc.y += e.y; acc.z += e.z; acc.w += e.w;
        if (t == 0) Ec[(b * H + h) * N + i] = e.x;
        if (i == 0) *reinterpret_cast<float4*>(E0 + (b * H + h) * N + t * 4) = e;
    }
    *reinterpret_cast<float4*>(G + ((size_t)b * N + i) * N + t * 4) = acc;
}

// 5 x (row-normalize, col-normalize) with G LDS-resident; fence-free 8-block barriers.
__global__ __launch_bounds__(TPB) void k_coop(const float* __restrict__ G,
                                              const float* __restrict__ E0,
                                              const float* __restrict__ Ec,
                                              float* __restrict__ partA,
                                              float* __restrict__ partB,
                                              float* __restrict__ c0pA,
                                              float* __restrict__ c0pB,
                                              float* __restrict__ rv,
                                              float* __restrict__ r0v,
                                              float* __restrict__ cv,
                                              float* __restrict__ c0v,
                                              int* __restrict__ counters) {
    __shared__ float Gs[RPB][N];   // 128 KB
    __shared__ float E0g[N];       // this block's head (h=g) row-0 slice
    __shared__ float vec[N];       // c values (row phase)
    __shared__ float EcS[H][RPB];  // Ec for owned rows
    __shared__ float rloc[RPB];
    __shared__ float c0rec[H];
    __shared__ float r0loc_s;

    const int blk = blockIdx.x;
    const int b = blk >> 3;
    const int g = blk & 7;
    const int rbase = g * RPB;
    const bool owner = (g == 0);
    const int tid = threadIdx.x;
    const int w = tid >> 6, lane = tid & 63;
    int* cnt = counters + b * 16;

    // ---- async stage G into LDS (wave-linear layout matches global_load_lds) ----
    {
        const float4* Gg = reinterpret_cast<const float4*>(G + ((size_t)(b * N) + rbase) * N);
        float4* Gl = reinterpret_cast<float4*>(&Gs[0][0]);
#pragma unroll
        for (int k = 0; k < RPB * N / 4 / TPB; ++k) {
            const int t = k * TPB + tid;
            __builtin_amdgcn_global_load_lds(
                (const __attribute__((address_space(1))) void*)(Gg + t),
                (__attribute__((address_space(3))) void*)(Gl + t),
                16, 0, 0);
        }
    }
    for (int t = tid; t < H * RPB; t += TPB)
        EcS[t / RPB][t % RPB] = Ec[(b * H + (t / RPB)) * N + rbase + (t % RPB)];
    E0g[tid] = E0[(b * H + g) * N + tid];
    const float E00g = Ec[(b * H + g) * N];  // E[b,g,0,0]
    __syncthreads();

    for (int it = 0; it < 5; ++it) {
        // ---------- row phase: r[b,i] and r0[b,h] ----------
        if (it == 0) {
            vec[tid] = (tid == 0) ? 0.0f : 1.0f;  // c = 1; j=0 handled via c0 term
            if (tid < H) c0rec[tid] = 1.0f;
        } else {
            const float* pr = (it & 1) ? partB : partA;
            pr += (size_t)b * 8 * N;
            float cs = 0.0f;
#pragma unroll
            for (int gg = 0; gg < 8; ++gg) cs += atomLoad(&pr[gg * N + tid]);
            vec[tid] = (tid == 0) ? 0.0f : 1.0f / cs;
            if (tid < H) {
                const float* qr = (it & 1) ? c0pB : c0pA;
                qr += b * 8 * H;
                float s = 0.0f;
#pragma unroll
                for (int gg = 0; gg < 8; ++gg) s += atomLoad(&qr[gg * H + tid]);
                c0rec[tid] = 1.0f / s;
            }
        }
        __syncthreads();
        float cj[8];
#pragma unroll
        for (int k = 0; k < 8; ++k) cj[k] = vec[lane + 64 * k];
#pragma unroll
        for (int r8 = 0; r8 < 8; ++r8) {
            const int il = w * 8 + r8;
            float pacc = 0.0f;
#pragma unroll
            for (int k = 0; k < 8; ++k) pacc += Gs[il][lane + 64 * k] * cj[k];
#pragma unroll
            for (int s = 32; s > 0; s >>= 1) pacc += __shfl_down(pacc, s, 64);
            if (lane == 0) {
                float s2 = pacc;
#pragma unroll
                for (int h = 0; h < H; ++h) s2 += EcS[h][il] * c0rec[h];
                float rva = 1.0f / s2;
                rloc[il] = rva;                 // garbage for owner il=0, masked below
                if (it == 4) rv[b * N + rbase + il] = rva;
            }
        }
        if (w == g) {   // r0 for head h=g
            float pacc = 0.0f;
#pragma unroll
            for (int k = 0; k < 8; ++k) pacc += E0g[lane + 64 * k] * cj[k];
#pragma unroll
            for (int s = 32; s > 0; s >>= 1) pacc += __shfl_down(pacc, s, 64);
            if (lane == 0) {
                float v = 1.0f / (pacc + E00g * c0rec[g]);
                r0loc_s = v;
                if (it == 4) r0v[b * H + g] = v;
            }
        }
        __syncthreads();
        // ---------- col phase: partial column sums ----------
        {
            float* pw = ((it + 1) & 1) ? partB : partA;
            float* qw = ((it + 1) & 1) ? c0pB : c0pA;
            const float r0l = r0loc_s;
            float acc = 0.0f;
            const int il0 = owner ? 1 : 0;  // global row 0 handled via E0 terms
#pragma unroll 8
            for (int il = il0; il < RPB; ++il) acc += Gs[il][tid] * rloc[il];
            acc += E0g[tid] * r0l;          // head g's i=0 contribution
            atomStore(&pw[((size_t)(b * 8) + g) * N + tid], acc);
            float q = EcS[w][lane] * ((owner && lane == 0) ? 0.0f : rloc[lane]);
            if (w == g && lane == 0) q += E00g * r0l;
#pragma unroll
            for (int s = 32; s > 0; s >>= 1) q += __shfl_down(q, s, 64);
            if (lane == 0) atomStore(&qw[(b * 8 + g) * H + w], q);
        }
        group_barrier(cnt, (it + 1) * 8);
    }
    // ---- finalize c factors (block g==0 of each b) ----
    if (owner) {
        const float* pr = partB + (size_t)b * 8 * N;   // (4+1)&1 == 1
        float cs = 0.0f;
#pragma unroll
        for (int gg = 0; gg < 8; ++gg) cs += atomLoad(&pr[gg * N + tid]);
        cv[b * N + tid] = (tid == 0) ? 1.0f : 1.0f / cs;
        if (tid < H) {
            const float* qr = c0pB + b * 8 * H;
            float s = 0.0f;
#pragma unroll
            for (int gg = 0; gg < 8; ++gg) s += atomLoad(&qr[gg * H + tid]);
            c0v[b * H + tid] = 1.0f / s;
        }
    }
}

// 4 independent float4s per thread + non-temporal load/store (no reuse of in/out).
__global__ __launch_bounds__(256) void k_final(const float* __restrict__ in,
                                               const float* __restrict__ rv,
                                               const float* __restrict__ r0v,
                                               const float* __restrict__ cv,
                                               const float* __restrict__ c0v,
                                               float* __restrict__ out) {
    const size_t v0 = (size_t)blockIdx.x * 1024 + threadIdx.x;
#pragma unroll
    for (int s = 0; s < 4; ++s) {
        const size_t v = v0 + (size_t)s * 256;   // float4 index
        const int j4 = (int)(v & 127);
        size_t rest = v >> 7;
        const int i = (int)(rest & 511); rest >>= 9;
        const int h = (int)(rest & 7);
        const int b = (int)(rest >> 3);
        const float R = (i == 0) ? r0v[b * H + h] : rv[b * N + i];
        const f32x4 x = __builtin_nontemporal_load(reinterpret_cast<const f32x4*>(in) + v);
        float4 cl = reinterpret_cast<const float4*>(cv + b * N)[j4];
        if (j4 == 0) cl.x = c0v[b * H + h];
        f32x4 o;
        o.x = __expf(x.x) * R * cl.x;
        o.y = __expf(x.y) * R * cl.y;
        o.z = __expf(x.z) * R * cl.z;
        o.w = __expf(x.w) * R * cl.w;
        __builtin_nontemporal_store(o, reinterpret_cast<f32x4*>(out) + v);
    }
}

extern "C" void kernel_launch(void* const* d_in, const int* in_sizes, int n_in,
                              void* d_out, int out_size, void* d_ws, size_t ws_size,
                              hipStream_t stream) {
    (void)in_sizes; (void)n_in; (void)out_size; (void)ws_size;
    const float* in = (const float*)d_in[0];
    float* out = (float*)d_out;
    float* ws = (float*)d_ws;

    // persistent factor vectors (must survive into k_final) live in ws
    float* rv  = ws;           // B*N
    float* cv  = ws + 16384;   // B*N
    float* r0v = ws + 32768;   // B*H
    float* c0v = ws + 33024;   // B*H
    int* counters = (int*)(ws + 33280);  // 32 groups x 16 ints

    // pre-final scratch lives in the tail of d_out (fully consumed before k_final writes)
    float* G   = out;             // B*N*N
    float* E0  = out + OFF_E0;    // B*H*N
    float* Ec  = out + OFF_EC;    // B*H*N
    float* pA  = out + OFF_PA;    // B*8*N
    float* pB  = out + OFF_PB;    // B*8*N
    float* c0A = out + OFF_C0A;   // B*8*H
    float* c0B = out + OFF_C0B;   // B*8*H

    hipMemsetAsync(counters, 0, B * 16 * sizeof(int), stream);

    k_build<<<dim3(N, B), 128, 0, stream>>>(in, G, E0, Ec);

    void* args[] = {(void*)&G, (void*)&E0, (void*)&Ec, (void*)&pA, (void*)&pB,
                    (void*)&c0A, (void*)&c0B, (void*)&rv, (void*)&r0v,
                    (void*)&cv, (void*)&c0v, (void*)&counters};
    hipLaunchCooperativeKernel(reinterpret_cast<void*>(k_coop), dim3(NBLK), dim3(TPB),
                               args, 0, stream);

    k_final<<<16384, 256, 0, stream>>>(in, rv, r0v, cv, c0v, out);
}